// Round 6
// baseline (10130.943 us; speedup 1.0000x reference)
//
#include <hip/hip_runtime.h>
#include <cstdint>
#include <cstddef>

#define T_ 256
#define B_ 128
#define E_ 512
#define H_ 1024
#define BH (B_*H_)

#define AGENT __HIP_MEMORY_SCOPE_AGENT
#define RLX   __ATOMIC_RELAXED

typedef _Float16 v8h __attribute__((ext_vector_type(8)));
typedef float    v4f __attribute__((ext_vector_type(4)));
typedef unsigned long long u64;

__device__ __forceinline__ float sigmoidf_(float x){ return 1.0f/(1.0f+__expf(-x)); }
__device__ __forceinline__ float tanhf_(float x){ return 1.0f - 2.0f/(__expf(2.0f*x)+1.0f); }

// ---------------------------------------------------------------------------
// Two-level grid barrier, PAGE-STRIDED. Round-5 bug: all barrier lines lived
// in 8.4KB (1-3 fabric interleave units) -> one/two L3 slices served ALL
// 256 RMWs + ~700 polls/µs -> queueing -> ~30-40µs/step floor (the measured
// plateau of rounds 2-5). Fix: 4352B stride puts each leaf/rel line in its
// own interleave unit; <=8 RMWs serialize per line, <=8 pollers per page.
// ---------------------------------------------------------------------------
#define BAR_STRIDE 1088   // uints = 4352 B (non-pow2 to decorrelate slice hash)
__device__ __forceinline__ void grid_barrier(unsigned int* bar, int blk, unsigned int k1) {
    __syncthreads();   // all waves drain vmcnt -> h stores acked at coherence point
    if (threadIdx.x == 0) {
        const int g = blk >> 3;
        unsigned int* leaf = bar + (size_t)g * BAR_STRIDE;
        unsigned int* root = bar + (size_t)32 * BAR_STRIDE;
        unsigned int* rel  = bar + (size_t)(33 + g) * BAR_STRIDE;
        unsigned int old = __hip_atomic_fetch_add(leaf, 1u, RLX, AGENT);
        if ((old & 7u) == 7u) {                      // group finisher (8/group)
            unsigned int ro = __hip_atomic_fetch_add(root, 1u, RLX, AGENT);
            if ((ro & 31u) == 31u) {                 // last of 32 groups
#pragma unroll 4
                for (int j = 0; j < 32; ++j)         // broadcast, 32 distinct pages
                    __hip_atomic_store(bar + (size_t)(33 + j) * BAR_STRIDE, k1, RLX, AGENT);
            } else {
                while (__hip_atomic_load(rel, RLX, AGENT) < k1)
                    __builtin_amdgcn_s_sleep(4);
            }
        } else {
            while (__hip_atomic_load(rel, RLX, AGENT) < k1)
                __builtin_amdgcn_s_sleep(4);
        }
    }
    __syncthreads();
}

#define APITCH 520   // halves; 1040B rows
#define OPITCH 72

// Stage one 16-row x 512-half A chunk into registers (64B/thread as 8x8B).
// AT: device-scope scoped loads (h buffers, L3-coherent, still line-coalesced).
template<bool AT>
__device__ __forceinline__ void stage_load(u64 (&regs)[8],
    const _Float16* __restrict__ src, int ap, int row0, int kbase, int tid) {
    const int r = tid >> 4, b = tid & 15;
    const _Float16* p = src + (size_t)(row0 + r) * ap + kbase + b * 4;
#pragma unroll
    for (int i = 0; i < 8; ++i) {
        const u64* q = (const u64*)(p + i * 64);
        regs[i] = AT ? __hip_atomic_load(q, RLX, AGENT) : *q;
    }
}
__device__ __forceinline__ void stage_write(const u64 (&regs)[8],
    _Float16 (&buf)[16][APITCH], int tid) {
    const int r = tid >> 4, b = tid & 15;
#pragma unroll
    for (int i = 0; i < 8; ++i)
        *(u64*)&buf[r][b * 4 + i * 64] = regs[i];
}

// 16 ksteps (512 halves) of 16x16x32 f16 MFMA over a staged A chunk.
// B direct from L2 (cached, XCD-resident slice). 3 gates.
__device__ __forceinline__ void mfma_chunk(v4f& aR, v4f& aZ, v4f& aN,
    const _Float16 (&buf)[16][APITCH],
    const _Float16* __restrict__ Bw, int bp, int bcol, int kbase, int lane) {
    const int r = lane & 15, hi = lane >> 4;
    const _Float16* bb = Bw + (size_t)(bcol + r) * bp + kbase + hi * 8;
    const size_t gs = (size_t)H_ * bp;
#pragma unroll
    for (int sub = 0; sub < 2; ++sub) {
        v8h B0[8], B1[8], B2[8], Av[8];
#pragma unroll
        for (int j = 0; j < 8; ++j) {
            const int kk = (sub * 8 + j) * 32;
            B0[j] = *(const v8h*)(bb + kk);
            B1[j] = *(const v8h*)(bb + gs + kk);
            B2[j] = *(const v8h*)(bb + 2 * gs + kk);
            Av[j] = *(const v8h*)&buf[r][sub * 256 + j * 32 + hi * 8];
        }
#pragma unroll
        for (int j = 0; j < 8; ++j) {
            aR = __builtin_amdgcn_mfma_f32_16x16x32_f16(Av[j], B0[j], aR, 0,0,0);
            aZ = __builtin_amdgcn_mfma_f32_16x16x32_f16(Av[j], B1[j], aZ, 0,0,0);
            aN = __builtin_amdgcn_mfma_f32_16x16x32_f16(Av[j], B2[j], aN, 0,0,0);
        }
    }
}

// ---------------------------------------------------------------------------
// Persistent fused 2-layer packed-seq GRU. 256 WGs x 256 thr, 1 WG/CU.
// WGs 0..127: layer0 @ t=k; 128..255: layer1 @ t=k-1. One barrier per step.
// WG tile 16 rows x 64 cols; wave w owns cols [w*16,+16) -> no K-split reduce.
// h exchange: 8B relaxed agent scoped ld/st (no RMW) -> L3-coherent,
// no cache-wide maintenance -> weights stay L2-resident (per-XCD ~2.7MB).
// ---------------------------------------------------------------------------
__global__ __launch_bounds__(256, 1) void gru_persist(
    const int* __restrict__ bs, const _Float16* __restrict__ x16,
    const _Float16* __restrict__ Wi0, const _Float16* __restrict__ Wh0,
    const _Float16* __restrict__ Wi1, const _Float16* __restrict__ Wh1,
    const float* __restrict__ bias,
    float* __restrict__ h0f, float* __restrict__ h1f,
    _Float16* __restrict__ h0h, _Float16* __restrict__ h1h,
    _Float16* __restrict__ hn0,
    unsigned int* __restrict__ bar)
{
    __shared__ _Float16 Abuf[2][16][APITCH];
    __shared__ _Float16 Otile[2][16][OPITCH];   // [0]=h-shadow, [1]=hn0
    __shared__ int bs_l[T_];

    const int blk = blockIdx.x;
    const int phase = blk >> 7, bl = blk & 127;
    const int xcd = bl & 7, idx = bl >> 3;      // idx in [0,16)
    const int rtile = (idx & 7) * 16;
    const int ctile = (xcd * 2 + (idx >> 3)) * 64;
    const int tid = threadIdx.x, lane = tid & 63, w = tid >> 6;

    bs_l[tid] = bs[tid];

    const float* bb = bias + phase * 4 * H_;
    const int colw = w * 16 + (lane & 15);      // [0,64) within tile
    const int col = ctile + colw;
    const float br_ = bb[col], bz_ = bb[H_ + col];
    const float bi_ = bb[2 * H_ + col], bh_ = bb[3 * H_ + col];
    float* hf = phase ? h1f : h0f;
    _Float16* hh = phase ? h1h : h0h;
    const int bcol = ctile + w * 16;
    __syncthreads();

    for (int k = 0; k <= T_; ++k) {
        const int t = phase ? (k - 1) : k;
        const bool run = phase ? (k > 0) : (k < T_);
        if (run) {
            const int bs_t = bs_l[t];
            if (rtile < bs_t) {
                const int pr = t & 1, pw = 1 - pr;
                v4f aR{0.f,0.f,0.f,0.f}, aZ{0.f,0.f,0.f,0.f};
                v4f aNi{0.f,0.f,0.f,0.f}, aNh{0.f,0.f,0.f,0.f};
                u64 regs[8];
                // Chained chunk pipeline: stage-load of chunk c+1 issues
                // before MFMAs of chunk c -> only chunk0 latency exposed.
                if (phase == 0) {
                    const _Float16* xr = x16 + (size_t)t * B_ * E_;
                    const _Float16* hr = h0h + (size_t)pr * BH;
                    stage_load<false>(regs, xr, E_, rtile, 0, tid);
                    __syncthreads(); stage_write(regs, Abuf[0], tid); __syncthreads();
                    stage_load<true>(regs, hr, H_, rtile, 0, tid);
                    mfma_chunk(aR, aZ, aNi, Abuf[0], Wi0, E_, bcol, 0, lane);
                    __syncthreads(); stage_write(regs, Abuf[1], tid); __syncthreads();
                    stage_load<true>(regs, hr, H_, rtile, 512, tid);
                    mfma_chunk(aR, aZ, aNh, Abuf[1], Wh0, H_, bcol, 0, lane);
                    __syncthreads(); stage_write(regs, Abuf[0], tid); __syncthreads();
                    mfma_chunk(aR, aZ, aNh, Abuf[0], Wh0, H_, bcol, 512, lane);
                } else {
                    const _Float16* nr = hn0 + (size_t)pr * BH;
                    const _Float16* hr = h1h + (size_t)pr * BH;
                    stage_load<true>(regs, nr, H_, rtile, 0, tid);
                    __syncthreads(); stage_write(regs, Abuf[0], tid); __syncthreads();
                    stage_load<true>(regs, nr, H_, rtile, 512, tid);
                    mfma_chunk(aR, aZ, aNi, Abuf[0], Wi1, H_, bcol, 0, lane);
                    __syncthreads(); stage_write(regs, Abuf[1], tid); __syncthreads();
                    stage_load<true>(regs, hr, H_, rtile, 0, tid);
                    mfma_chunk(aR, aZ, aNi, Abuf[1], Wi1, H_, bcol, 512, lane);
                    __syncthreads(); stage_write(regs, Abuf[0], tid); __syncthreads();
                    stage_load<true>(regs, hr, H_, rtile, 512, tid);
                    mfma_chunk(aR, aZ, aNh, Abuf[0], Wh1, H_, bcol, 0, lane);
                    __syncthreads(); stage_write(regs, Abuf[1], tid); __syncthreads();
                    mfma_chunk(aR, aZ, aNh, Abuf[1], Wh1, H_, bcol, 512, lane);
                }
                // epilogue: C layout col=lane&15, row=(lane>>4)*4+reg
                const int q = lane >> 4;
#pragma unroll
                for (int reg = 0; reg < 4; ++reg) {
                    const int rowt = q * 4 + reg;           // [0,16)
                    const int row = rtile + rowt;
                    const size_t off = (size_t)row * H_ + col;
                    const float hprev = hf[off];
                    const float rr = sigmoidf_(aR[reg] + br_);
                    const float zz = sigmoidf_(aZ[reg] + bz_);
                    const float nn = tanhf_(aNi[reg] + bi_ + rr * (aNh[reg] + bh_));
                    const float hnew = (1.0f - zz) * nn + zz * hprev;
                    const bool act = row < bs_t;
                    Otile[0][rowt][colw] = (_Float16)(act ? hnew : hprev);
                    if (phase == 0) Otile[1][rowt][colw] = (_Float16)hnew;
                    if (act) hf[off] = hnew;
                }
                __syncthreads();
                // publish tiles: coalesced 8B device-scope plain-scoped stores
                {
                    const int r = tid >> 4, c4 = (tid & 15) * 4;
                    const size_t goff = (size_t)(rtile + r) * H_ + ctile + c4;
                    _Float16* hh_w = hh + (size_t)pw * BH;
                    u64 v0 = *(const u64*)&Otile[0][r][c4];
                    __hip_atomic_store((u64*)(hh_w + goff), v0, RLX, AGENT);
                    if (phase == 0) {
                        _Float16* hn0w = hn0 + (size_t)pr * BH;
                        u64 v1 = *(const u64*)&Otile[1][r][c4];
                        __hip_atomic_store((u64*)(hn0w + goff), v1, RLX, AGENT);
                    }
                }
            }
        }
        grid_barrier(bar, blk, (unsigned)(k + 1));
    }
}

// ---------------------------------------------------------------------------
__global__ void cvt_f32_f16(const float* __restrict__ s, _Float16* __restrict__ d, int n) {
    int i = (blockIdx.x * 256 + threadIdx.x) * 8;
    if (i >= n) return;
    float4 v0 = *(const float4*)(s + i);
    float4 v1 = *(const float4*)(s + i + 4);
    v8h o = { (_Float16)v0.x, (_Float16)v0.y, (_Float16)v0.z, (_Float16)v0.w,
              (_Float16)v1.x, (_Float16)v1.y, (_Float16)v1.z, (_Float16)v1.w };
    *(v8h*)(d + i) = o;
}

__global__ void prep_bias(const float* __restrict__ bi0, const float* __restrict__ bh0,
                          const float* __restrict__ bi1, const float* __restrict__ bh1,
                          float* __restrict__ bias) {
    int tid = blockIdx.x * 256 + threadIdx.x;   // 2048 threads
    int l = tid >> 10, j = tid & 1023;
    const float* bi = l ? bi1 : bi0;
    const float* bh = l ? bh1 : bh0;
    float* o = bias + l * 4 * H_;
    o[j]          = bi[j] + bh[j];
    o[H_ + j]     = bi[H_ + j] + bh[H_ + j];
    o[2 * H_ + j] = bi[2 * H_ + j];
    o[3 * H_ + j] = bh[2 * H_ + j];
}

__global__ void gather_out(const float* __restrict__ h0f, const float* __restrict__ h1f,
                           const int* __restrict__ unsorted, float* __restrict__ out) {
    int rowid = blockIdx.x;          // 256 = L*B
    int l = rowid >> 7, b = rowid & 127;
    int src = unsorted[b];
    const float* s = (l ? h1f : h0f) + (size_t)src * H_;
    float* o = out + (size_t)rowid * H_;
    int c = threadIdx.x * 4;
    *(float4*)(o + c) = *(const float4*)(s + c);
}

// ---------------------------------------------------------------------------
extern "C" void kernel_launch(void* const* d_in, const int* in_sizes, int n_in,
                              void* d_out, int out_size, void* d_ws, size_t ws_size,
                              hipStream_t stream) {
    const float* x    = (const float*)d_in[0];
    const float* Wi0f = (const float*)d_in[1];
    const float* Wh0f = (const float*)d_in[2];
    const float* bi0  = (const float*)d_in[3];
    const float* bh0  = (const float*)d_in[4];
    const float* Wi1f = (const float*)d_in[5];
    const float* Wh1f = (const float*)d_in[6];
    const float* bi1  = (const float*)d_in[7];
    const float* bh1  = (const float*)d_in[8];
    const int*  bs       = (const int*)d_in[9];
    const int*  unsorted = (const int*)d_in[10];
    float* out = (float*)d_out;

    char* ws = (char*)d_ws;
    size_t off = 0;
    auto alloc = [&](size_t bytes) -> char* {
        char* p = ws + off;
        off += (bytes + 255) & ~(size_t)255;
        return p;
    };
    _Float16* x16 = (_Float16*)alloc((size_t)T_ * B_ * E_ * 2);
    _Float16* Wi0 = (_Float16*)alloc((size_t)3 * H_ * E_ * 2);
    _Float16* Wh0 = (_Float16*)alloc((size_t)3 * H_ * H_ * 2);
    _Float16* Wi1 = (_Float16*)alloc((size_t)3 * H_ * H_ * 2);
    _Float16* Wh1 = (_Float16*)alloc((size_t)3 * H_ * H_ * 2);
    float*    bias = (float*)alloc(2 * 4 * H_ * 4);
    char* zbase = ws + off;                       // zero-init block start
    unsigned int* bar = (unsigned int*)alloc((size_t)66 * BAR_STRIDE * 4);
    float*    h0f = (float*)alloc((size_t)BH * 4);
    float*    h1f = (float*)alloc((size_t)BH * 4);
    _Float16* h0h = (_Float16*)alloc((size_t)2 * BH * 2);
    _Float16* h1h = (_Float16*)alloc((size_t)2 * BH * 2);
    _Float16* hn0 = (_Float16*)alloc((size_t)2 * BH * 2);
    size_t zbytes = (size_t)((ws + off) - zbase);

    hipMemsetAsync(zbase, 0, zbytes, stream);

    cvt_f32_f16<<<(T_ * B_ * E_) / 2048, 256, 0, stream>>>(x, x16, T_ * B_ * E_);
    cvt_f32_f16<<<(3 * H_ * E_) / 2048, 256, 0, stream>>>(Wi0f, Wi0, 3 * H_ * E_);
    cvt_f32_f16<<<(3 * H_ * H_) / 2048, 256, 0, stream>>>(Wh0f, Wh0, 3 * H_ * H_);
    cvt_f32_f16<<<(3 * H_ * H_) / 2048, 256, 0, stream>>>(Wi1f, Wi1, 3 * H_ * H_);
    cvt_f32_f16<<<(3 * H_ * H_) / 2048, 256, 0, stream>>>(Wh1f, Wh1, 3 * H_ * H_);
    prep_bias<<<8, 256, 0, stream>>>(bi0, bh0, bi1, bh1, bias);

    gru_persist<<<256, 256, 0, stream>>>(bs, x16, Wi0, Wh0, Wi1, Wh1, bias,
                                         h0f, h1f, h0h, h1h, hn0, bar);

    gather_out<<<256, 256, 0, stream>>>(h0f, h1f, unsorted, out);
}